// Round 2
// 388.995 us; speedup vs baseline: 1.0809x; 1.0809x over previous
//
#include <hip/hip_runtime.h>

// ProgressiveFocusedAttention, MI355X/gfx950 — fully fused per-window kernel.
// B=4, H=W=128, C=192, 6 heads x 32, window 8x8 (64 tokens), shift 4. 1024 windows.
// Outputs: out (4,128,128,192) fp32 then attn (1024,6,64,64) fp32 (concatenated).
//
// R5: R4's fusion structure with all unproven mechanisms reverted to R3-proven ones:
//  - manual RTNE f2bf/pack2 everywhere (no v_cvt_pk_bf16_f32 inline asm)
//  - LePE conv via LDS gather (no __shfl), in-place per independent channel
//  - __syncthreads() between every LDS produce->consume phase
//
// MFMA 16x16x32 bf16 layouts (HW-verified across R0-R3):
//   A[m][k]: m = lane&15, k = (lane>>4)*8 + j
//   B[k][n]: n = lane&15, k = (lane>>4)*8 + j
//   D[r][c]: c = lane&15, r = (lane>>4)*4 + reg
//
// LDS map (shorts), 51200 total (102,400 B):
//   [0,12800)      xw   [64][200]   x-window bf16 (dead after P1)
//   [12800,37376)  per head h (4096): q [64][32] @+0, k [64][32] @+2048;
//                  after QK^T overlaid by P_h [64][64]
//   [37376,51200)  per head h (2304): vt [32][72] (v^T, LePE'd in place);
//                  after PV overlaid by o_h [64][32]

#define SCALE 0.17677669529663687f

typedef __attribute__((ext_vector_type(8))) short short8;
typedef __attribute__((ext_vector_type(4))) float f32x4;

__device__ __forceinline__ unsigned short f2bf(float f) {
    unsigned int u = __float_as_uint(f);
    u = (u + 0x7FFFu + ((u >> 16) & 1u)) >> 16;   // round-to-nearest-even
    return (unsigned short)u;
}
__device__ __forceinline__ float bf2f(unsigned short h) {
    return __uint_as_float(((unsigned int)h) << 16);
}
__device__ __forceinline__ unsigned int pack2(float a, float b) {
    return (unsigned int)f2bf(a) | ((unsigned int)f2bf(b) << 16);
}

// ---------------------------------------------------------------- K0: pack
__global__ __launch_bounds__(256) void k0_pack(const float* __restrict__ qkv_w,
                                               const float* __restrict__ proj_w,
                                               unsigned short* __restrict__ qkvp,
                                               unsigned short* __restrict__ projp) {
    int gid = blockIdx.x * 256 + threadIdx.x;   // grid covers 6*36*64 + 6*12*64 = 18432
    if (gid < 6 * 36 * 64) {
        int lane = gid & 63, tile = gid >> 6;
        int nt = tile % 36, ks = tile / 36;
        int row = ks * 32 + (lane >> 4) * 8, col = nt * 16 + (lane & 15);
        const float* w = qkv_w + (size_t)row * 576 + col;
        uint4 o;
        o.x = pack2(w[0 * 576], w[1 * 576]);
        o.y = pack2(w[2 * 576], w[3 * 576]);
        o.z = pack2(w[4 * 576], w[5 * 576]);
        o.w = pack2(w[6 * 576], w[7 * 576]);
        *(uint4*)(qkvp + (size_t)gid * 8) = o;
    } else {
        int g = gid - 6 * 36 * 64;
        int lane = g & 63, tile = g >> 6;
        int nt = tile % 12, ks = tile / 12;
        int row = ks * 32 + (lane >> 4) * 8, col = nt * 16 + (lane & 15);
        const float* w = proj_w + (size_t)row * 192 + col;
        uint4 o;
        o.x = pack2(w[0 * 192], w[1 * 192]);
        o.y = pack2(w[2 * 192], w[3 * 192]);
        o.z = pack2(w[4 * 192], w[5 * 192]);
        o.w = pack2(w[6 * 192], w[7 * 192]);
        *(uint4*)(projp + (size_t)g * 8) = o;
    }
}

// ---------------------------------------------------------------- fused kernel
#define LDS_XW 0
#define LDS_QK 12800
#define LDS_VT 37376

__global__ __launch_bounds__(384, 2) void k_fused(
    const float* __restrict__ x, const float* __restrict__ prev,
    const float* __restrict__ qkv_b, const float* __restrict__ lepe_w,
    const float* __restrict__ lepe_b, const float* __restrict__ proj_b,
    const unsigned short* __restrict__ qkvp, const unsigned short* __restrict__ projp,
    float* __restrict__ out, float* __restrict__ attn)
{
    __shared__ unsigned short lds[51200];   // 102,400 B
    const int wb = blockIdx.x;
    const int b = wb >> 8, wh = (wb >> 4) & 15, wwi = wb & 15;
    const int t = threadIdx.x;
    const int lane = t & 63, h = t >> 6, quad = lane >> 4, l16 = lane & 15;
    const f32x4 fz = {0.f, 0.f, 0.f, 0.f};

    // ---- P0: shifted-window load, fp32 -> bf16, fully coalesced
#pragma unroll
    for (int kk = 0; kk < 8; ++kk) {
        int f = kk * 384 + t;                 // float4 id within window, 0..3071
        int token = f / 48, c4 = f - token * 48;
        int i = token >> 3, j = token & 7;
        int hh = (wh * 8 + i + 4) & 127, wp = (wwi * 8 + j + 4) & 127;
        const float4 v4 = *(const float4*)(x + ((size_t)((b * 128 + hh) * 128 + wp)) * 192 + c4 * 4);
        unsigned int* d = (unsigned int*)&lds[LDS_XW + token * 200 + c4 * 4];
        d[0] = pack2(v4.x, v4.y);
        d[1] = pack2(v4.z, v4.w);
    }
    __syncthreads();

    // column-tile ids for this head: q:{2h,2h+1} k:{12+2h,13+2h} v:{24+2h,25+2h}
    const int ntg[6] = {2 * h, 2 * h + 1, 12 + 2 * h, 13 + 2 * h, 24 + 2 * h, 25 + 2 * h};

    unsigned short* qh  = &lds[LDS_QK + h * 4096];
    unsigned short* kh  = qh + 2048;
    unsigned short* vth = &lds[LDS_VT + h * 2304];

    // ---- P1: qkv_h = xw(64x192) @ W[:, head-h tiles]; 144 MFMA / wave
    {
        f32x4 acc[6][4];
#pragma unroll
        for (int j = 0; j < 6; ++j)
#pragma unroll
            for (int m = 0; m < 4; ++m) acc[j][m] = fz;

#pragma unroll
        for (int ks = 0; ks < 6; ++ks) {
            short8 a[4];
#pragma unroll
            for (int m = 0; m < 4; ++m)
                a[m] = *(const short8*)&lds[LDS_XW + (m * 16 + l16) * 200 + ks * 32 + quad * 8];
#pragma unroll
            for (int j = 0; j < 6; ++j) {
                short8 bf = *(const short8*)(qkvp + (((size_t)(ks * 36 + ntg[j]) * 64 + lane) << 3));
#pragma unroll
                for (int m = 0; m < 4; ++m)
                    acc[j][m] = __builtin_amdgcn_mfma_f32_16x16x32_bf16(a[m], bf, acc[j][m], 0, 0, 0);
            }
        }

        // epilogue: +bias -> bf16 -> q/k strips [token][ch], v -> vt [ch][token]
#pragma unroll
        for (int j = 0; j < 6; ++j) {
            float bias = qkv_b[ntg[j] * 16 + l16];
#pragma unroll
            for (int m = 0; m < 4; ++m) {
#pragma unroll
                for (int r = 0; r < 4; ++r) {
                    int token = m * 16 + quad * 4 + r;
                    unsigned short bv = f2bf(acc[j][m][r] + bias);
                    if (j < 2)      qh[token * 32 + j * 16 + l16] = bv;
                    else if (j < 4) kh[token * 32 + (j - 2) * 16 + l16] = bv;
                    else            vth[((j - 4) * 16 + l16) * 72 + token] = bv;
                }
            }
        }
    }
    __syncthreads();

    // ---- P2: LePE 3x3 depthwise conv (zero-pad inside window) + residual, in place.
    {
        const int ti = lane >> 3, tj = lane & 7;
        for (int ci = 0; ci < 32; ++ci) {
            int c = h * 32 + ci;
            const unsigned short* vr = vth + ci * 72;
            float sum = bf2f(vr[lane]) + lepe_b[c];
#pragma unroll
            for (int di = -1; di <= 1; ++di)
#pragma unroll
                for (int dj = -1; dj <= 1; ++dj) {
                    int ii = ti + di, jj = tj + dj;
                    if (ii >= 0 && ii < 8 && jj >= 0 && jj < 8)
                        sum += bf2f(vr[ii * 8 + jj]) * lepe_w[((di + 1) * 3 + (dj + 1)) * 192 + c];
                }
            vth[ci * 72 + lane] = f2bf(sum);
        }
    }
    __syncthreads();

    // ---- P3: QK^T (whole head per wave: 4x4 tiles, K=32 in one MFMA step)
    f32x4 s4[4][4];
    {
        short8 aq[4];
#pragma unroll
        for (int m = 0; m < 4; ++m)
            aq[m] = *(const short8*)(qh + (m * 16 + l16) * 32 + quad * 8);
#pragma unroll
        for (int nt = 0; nt < 4; ++nt) {
            short8 bk = *(const short8*)(kh + (nt * 16 + l16) * 32 + quad * 8);
#pragma unroll
            for (int m = 0; m < 4; ++m)
                s4[m][nt] = __builtin_amdgcn_mfma_f32_16x16x32_bf16(aq[m], bk, fz, 0, 0, 0);
        }
    }

    // ---- P4: gate with prev, softmax, write attn (fp32), stage P (bf16) over q+k.
    const float* pvm = prev + (((size_t)wb * 6 + h) << 12);
    float* aom = attn + (((size_t)wb * 6 + h) << 12);
    unsigned short* Ph = qh;                      // [64][64] overlay
#pragma unroll
    for (int m = 0; m < 4; ++m) {
        float e[4][4], inv[4];
#pragma unroll
        for (int r = 0; r < 4; ++r) {
            int row = m * 16 + quad * 4 + r;
            float ps = 0.f;
#pragma unroll
            for (int nt = 0; nt < 4; ++nt) {
                float sg = s4[m][nt][r] * SCALE * pvm[row * 64 + nt * 16 + l16];
                float ev = __expf(sg);
                e[r][nt] = ev; ps += ev;
            }
            ps += __shfl_xor(ps, 1); ps += __shfl_xor(ps, 2);
            ps += __shfl_xor(ps, 4); ps += __shfl_xor(ps, 8);
            inv[r] = 1.0f / ps;
        }
#pragma unroll
        for (int r = 0; r < 4; ++r) {
            int row = m * 16 + quad * 4 + r;
#pragma unroll
            for (int nt = 0; nt < 4; ++nt) {
                float av = e[r][nt] * inv[r];
                aom[row * 64 + nt * 16 + l16] = av;
                Ph[row * 64 + nt * 16 + l16] = f2bf(av);
            }
        }
    }
    __syncthreads();

    // ---- P5: PV: out_h(64x32) = P(64x64) @ v_h(64x32); stage o_h over dead vt strip
    {
        f32x4 o2[4][2];
#pragma unroll
        for (int m = 0; m < 4; ++m) { o2[m][0] = fz; o2[m][1] = fz; }
#pragma unroll
        for (int ks = 0; ks < 2; ++ks) {
            short8 ap[4];
#pragma unroll
            for (int m = 0; m < 4; ++m)
                ap[m] = *(const short8*)(Ph + (m * 16 + l16) * 64 + ks * 32 + quad * 8);
#pragma unroll
            for (int n2 = 0; n2 < 2; ++n2) {
                short8 bv = *(const short8*)(vth + (n2 * 16 + l16) * 72 + ks * 32 + quad * 8);
#pragma unroll
                for (int m = 0; m < 4; ++m)
                    o2[m][n2] = __builtin_amdgcn_mfma_f32_16x16x32_bf16(ap[m], bv, o2[m][n2], 0, 0, 0);
            }
        }
        unsigned short* oh = vth;                 // [64][32] overlay
#pragma unroll
        for (int m = 0; m < 4; ++m)
#pragma unroll
            for (int n2 = 0; n2 < 2; ++n2)
#pragma unroll
                for (int r = 0; r < 4; ++r)
                    oh[(m * 16 + quad * 4 + r) * 32 + n2 * 16 + l16] = f2bf(o2[m][n2][r]);
    }
    __syncthreads();   // all heads' o_h staged

    // ---- P6: proj: out(64x192) = o(64x192) @ proj_w; wave h owns 2 N-tiles.
    {
        f32x4 p3[2][4];
#pragma unroll
        for (int n = 0; n < 2; ++n)
#pragma unroll
            for (int m = 0; m < 4; ++m) p3[n][m] = fz;

#pragma unroll
        for (int ks = 0; ks < 6; ++ks) {
            const unsigned short* ob = &lds[LDS_VT + ks * 2304];   // head-ks o block [64][32]
            short8 a3[4];
#pragma unroll
            for (int m = 0; m < 4; ++m)
                a3[m] = *(const short8*)(ob + (m * 16 + l16) * 32 + quad * 8);
#pragma unroll
            for (int n = 0; n < 2; ++n) {
                short8 bf = *(const short8*)(projp + (((size_t)(ks * 12 + h * 2 + n) * 64 + lane) << 3));
#pragma unroll
                for (int m = 0; m < 4; ++m)
                    p3[n][m] = __builtin_amdgcn_mfma_f32_16x16x32_bf16(a3[m], bf, p3[n][m], 0, 0, 0);
            }
        }
#pragma unroll
        for (int n = 0; n < 2; ++n) {
            int col = (h * 2 + n) * 16 + l16;
            float bias = proj_b[col];
#pragma unroll
            for (int m = 0; m < 4; ++m)
#pragma unroll
                for (int r = 0; r < 4; ++r) {
                    int token = m * 16 + quad * 4 + r;
                    int i = token >> 3, j = token & 7;
                    int hh = (wh * 8 + i + 4) & 127, wp = (wwi * 8 + j + 4) & 127;
                    out[((size_t)((b * 128 + hh) * 128 + wp)) * 192 + col] = p3[n][m][r] + bias;
                }
        }
    }
}

// ---------------------------------------------------------------- launch
extern "C" void kernel_launch(void* const* d_in, const int* in_sizes, int n_in,
                              void* d_out, int out_size, void* d_ws, size_t ws_size,
                              hipStream_t stream) {
    const float* x      = (const float*)d_in[0];
    const float* prev   = (const float*)d_in[1];
    const float* qkv_w  = (const float*)d_in[2];
    const float* qkv_b  = (const float*)d_in[3];
    const float* proj_w = (const float*)d_in[4];
    const float* proj_b = (const float*)d_in[5];
    const float* lepe_w = (const float*)d_in[6];
    const float* lepe_b = (const float*)d_in[7];

    float* out  = (float*)d_out;
    float* attn = out + (size_t)4 * 128 * 128 * 192;   // second output, concatenated

    char* ws = (char*)d_ws;
    const size_t SZ_QKVP = 192 * 576 * 2;              // 221184
    unsigned short* qkvp  = (unsigned short*)(ws);
    unsigned short* projp = (unsigned short*)(ws + SZ_QKVP);

    k0_pack<<<72, 256, 0, stream>>>(qkv_w, proj_w, qkvp, projp);
    k_fused<<<1024, 384, 0, stream>>>(x, prev, qkv_b, lepe_w, lepe_b, proj_b,
                                      qkvp, projp, out, attn);
}